// Round 3
// baseline (1611.162 us; speedup 1.0000x reference)
//
#include <hip/hip_runtime.h>
#include <hip/hip_bf16.h>

// CoaT factorized attention + conv rel-pos-enc. B=8 N=3137 C=768 h=8 c=96 H=W=56.
// All harness tensors are FLOAT32 (per reference). Compute uses bf16 MFMA with
// f32->bf16 conversion at staging; intermediates in ws are bf16; accum fp32.

#define BB 8
#define NN 3137
#define HH 8
#define CH 96
#define HW 3136
#define IMG 56
#define MTOK (BB*NN)   // 25096

typedef __bf16 bf16x8 __attribute__((ext_vector_type(8)));
typedef unsigned short u16x8 __attribute__((ext_vector_type(8)));
typedef float  f32x4  __attribute__((ext_vector_type(4)));
typedef float  f32x8  __attribute__((ext_vector_type(8)));

__device__ __forceinline__ bf16x8 cvt_f32x8_bf16(f32x8 v) {
    return __builtin_convertvector(v, bf16x8);
}

// ---------------- GEMM (NT): C[M,Nd] = A[M,K](lda) @ W[Nd,K]^T + bias ----------------
// 128x128 block tile, BK=32, 4 waves each 64x64 (4x4 of 16x16x32 mfma).
// A_F32: A is float32 (converted to bf16 at staging); else A is bf16 (u16).
// OUT_F32: C is float32; else bf16.
template<bool A_F32, bool OUT_F32>
__global__ __launch_bounds__(256) void gemm_nt(
    const void* __restrict__ Aptr, int lda,
    const float* __restrict__ W,
    const float* __restrict__ bias,
    void* __restrict__ Cptr, int ldc,
    int M, int Nd, int K)
{
    __shared__ alignas(16) unsigned short As[128*32];
    __shared__ alignas(16) unsigned short Bs[128*32];
    const int tid  = threadIdx.x;
    const int n0   = blockIdx.x * 128;
    const int m0   = blockIdx.y * 128;
    const int lane = tid & 63;
    const int wave = tid >> 6;
    const int wm   = (wave >> 1) * 64;
    const int wn   = (wave & 1) * 64;
    const int lr   = lane & 15;
    const int quad = lane >> 4;

    // staging: slot s in [0,512): row = s>>2, kcol = (s&3)*8 ; 8 elements per slot
    const int r0 = tid >> 2, c0 = (tid & 3) * 8;
    const int r1 = r0 + 64;
    int am0 = m0 + r0; if (am0 > M-1) am0 = M-1;
    int am1 = m0 + r1; if (am1 > M-1) am1 = M-1;
    const float* w0 = W + (size_t)(n0+r0)*K + c0;
    const float* w1 = W + (size_t)(n0+r1)*K + c0;
    unsigned short* lA0 = As + tid*8;
    unsigned short* lA1 = As + (tid+256)*8;
    unsigned short* lB0 = Bs + tid*8;
    unsigned short* lB1 = Bs + (tid+256)*8;

    const float* af0 = A_F32 ? ((const float*)Aptr + (size_t)am0*lda + c0) : nullptr;
    const float* af1 = A_F32 ? ((const float*)Aptr + (size_t)am1*lda + c0) : nullptr;
    const unsigned short* ab0 = A_F32 ? nullptr : ((const unsigned short*)Aptr + (size_t)am0*lda + c0);
    const unsigned short* ab1 = A_F32 ? nullptr : ((const unsigned short*)Aptr + (size_t)am1*lda + c0);

    f32x4 acc[4][4] = {};
    for (int k0 = 0; k0 < K; k0 += 32) {
        u16x8 ra0, ra1;
        if (A_F32) {
            ra0 = (u16x8)cvt_f32x8_bf16(*(const f32x8*)(af0 + k0));
            ra1 = (u16x8)cvt_f32x8_bf16(*(const f32x8*)(af1 + k0));
        } else {
            ra0 = *(const u16x8*)(ab0 + k0);
            ra1 = *(const u16x8*)(ab1 + k0);
        }
        const u16x8 rb0 = (u16x8)cvt_f32x8_bf16(*(const f32x8*)(w0 + k0));
        const u16x8 rb1 = (u16x8)cvt_f32x8_bf16(*(const f32x8*)(w1 + k0));
        __syncthreads();                   // previous iter's LDS reads done
        *(u16x8*)lA0 = ra0;
        *(u16x8*)lA1 = ra1;
        *(u16x8*)lB0 = rb0;
        *(u16x8*)lB1 = rb1;
        __syncthreads();
        bf16x8 af[4], bfr[4];
#pragma unroll
        for (int i = 0; i < 4; ++i) {
            af[i]  = *(const bf16x8*)(As + (wm + i*16 + lr)*32 + quad*8);
            bfr[i] = *(const bf16x8*)(Bs + (wn + i*16 + lr)*32 + quad*8);
        }
#pragma unroll
        for (int i = 0; i < 4; ++i)
#pragma unroll
            for (int j = 0; j < 4; ++j)
                acc[i][j] = __builtin_amdgcn_mfma_f32_16x16x32_bf16(af[i], bfr[j], acc[i][j], 0, 0, 0);
    }
    // epilogue: C/D layout col=lane&15, row=quad*4+reg (m89-verified)
#pragma unroll
    for (int j = 0; j < 4; ++j) {
        const int col = n0 + wn + j*16 + lr;
        const float bv = bias[col];
#pragma unroll
        for (int i = 0; i < 4; ++i) {
#pragma unroll
            for (int r = 0; r < 4; ++r) {
                const int row = m0 + wm + i*16 + quad*4 + r;
                if (row < M) {
                    const float v = acc[i][j][r] + bv;
                    if (OUT_F32)
                        ((float*)Cptr)[(size_t)row*ldc + col] = v;
                    else
                        ((__hip_bfloat16*)Cptr)[(size_t)row*ldc + col] = __float2bfloat16(v);
                }
            }
        }
    }
}

// ---------------- softmax stats over tokens: per (b, h*96+c) column ----------------
__global__ __launch_bounds__(256) void ksm_stats(
    const __hip_bfloat16* __restrict__ qkv, float* __restrict__ stats)
{
    const int g  = blockIdx.x * 256 + threadIdx.x;     // 0..6143
    const int b  = g / 768, hc = g % 768;
    const __hip_bfloat16* base = qkv + (size_t)b*NN*2304 + 768 + hc;
    float m[4] = {-1e30f,-1e30f,-1e30f,-1e30f}, s[4] = {0.f,0.f,0.f,0.f};
    int n = 0;
    for (; n + 4 <= NN; n += 4) {
#pragma unroll
        for (int j = 0; j < 4; ++j) {
            const float x = __bfloat162float(base[(size_t)(n+j)*2304]);
            const float mn = fmaxf(m[j], x);
            s[j] = s[j]*__expf(m[j]-mn) + __expf(x-mn);
            m[j] = mn;
        }
    }
    for (; n < NN; ++n) {
        const float x = __bfloat162float(base[(size_t)n*2304]);
        const float mn = fmaxf(m[0], x);
        s[0] = s[0]*__expf(m[0]-mn) + __expf(x-mn);
        m[0] = mn;
    }
    const float M2 = fmaxf(fmaxf(m[0],m[1]), fmaxf(m[2],m[3]));
    const float S  = s[0]*__expf(m[0]-M2) + s[1]*__expf(m[1]-M2)
                   + s[2]*__expf(m[2]-M2) + s[3]*__expf(m[3]-M2);
    stats[2*g]   = M2;
    stats[2*g+1] = S;
}

__global__ __launch_bounds__(256) void zero_f32(float* __restrict__ p, int n)
{
    const int i = blockIdx.x * 256 + threadIdx.x;
    if (i < n) p[i] = 0.f;
}

// ---------------- kv[b,h,c,d] = sum_n softmax(k)[n,c] * v[n,d] ----------------
__global__ __launch_bounds__(256) void kv_accum(
    const __hip_bfloat16* __restrict__ qkv,
    const float* __restrict__ stats,
    float* __restrict__ kvmat)
{
    const int bh = blockIdx.x;              // 0..63
    const int b = bh >> 3, h = bh & 7;
    const int nstart = blockIdx.y * 393;
    int nend = nstart + 393; if (nend > NN) nend = NN;
    __shared__ float smax[96], srs[96];
    __shared__ float krow[4][96], vrow[4][96];
    const int t = threadIdx.x;
    if (t < 96) {
        const int g = b*768 + h*96 + t;
        smax[t] = stats[2*g];
        srs[t]  = 1.0f / stats[2*g+1];
    }
    __syncthreads();
    const int ci = (t >> 4) * 6;            // 16 groups of 6 over c
    const int di = (t & 15) * 6;            // 16 groups of 6 over d
    const __hip_bfloat16* kb = qkv + (size_t)b*NN*2304 + 768 + h*96;
    const __hip_bfloat16* vb = kb + 768;
    float acc[6][6] = {};
    for (int n = nstart; n < nend; n += 4) {
        __syncthreads();
        for (int idx = t; idx < 384; idx += 256) {
            const int r = idx / 96, j = idx % 96;
            const int nn = n + r;
            if (nn < nend) {
                krow[r][j] = __expf(__bfloat162float(kb[(size_t)nn*2304 + j]) - smax[j]) * srs[j];
                vrow[r][j] = __bfloat162float(vb[(size_t)nn*2304 + j]);
            } else { krow[r][j] = 0.f; vrow[r][j] = 0.f; }
        }
        __syncthreads();
#pragma unroll
        for (int r = 0; r < 4; ++r) {
            float kf[6], vf[6];
#pragma unroll
            for (int i = 0; i < 6; ++i) kf[i] = krow[r][ci+i];
#pragma unroll
            for (int j = 0; j < 6; ++j) vf[j] = vrow[r][di+j];
#pragma unroll
            for (int i = 0; i < 6; ++i)
#pragma unroll
                for (int j = 0; j < 6; ++j)
                    acc[i][j] += kf[i] * vf[j];
        }
    }
    float* outp = kvmat + (size_t)bh*9216;
#pragma unroll
    for (int i = 0; i < 6; ++i)
#pragma unroll
        for (int j = 0; j < 6; ++j)
            atomicAdd(&outp[(ci+i)*96 + (di+j)], acc[i][j]);
}

// ---------------- depthwise conv (SAME) on v_img, windows 3/5/7 by head group ----------------
template<int KS>
__device__ __forceinline__ void dw_run(
    const __hip_bfloat16* __restrict__ vb,   // &v[b, token1, ch], pixel stride 2304
    const float* __restrict__ wp, float bias,
    __hip_bfloat16* __restrict__ cvb,        // &cv[b,h,0,d], pixel stride 96
    int p0)
{
    constexpr int PAD = KS/2;
    float w[KS*KS];
#pragma unroll
    for (int i = 0; i < KS*KS; ++i) w[i] = wp[i];
    for (int i = 0; i < 8; ++i) {
        const int p = p0 + i;
        const int y = p / IMG, x = p % IMG;
        float acc = bias;
#pragma unroll
        for (int dy = 0; dy < KS; ++dy) {
            const int yy = y + dy - PAD;
#pragma unroll
            for (int dx = 0; dx < KS; ++dx) {
                const int xx = x + dx - PAD;
                if ((unsigned)yy < (unsigned)IMG && (unsigned)xx < (unsigned)IMG)
                    acc += w[dy*KS+dx] * __bfloat162float(vb[(size_t)(yy*IMG+xx)*2304]);
            }
        }
        cvb[(size_t)p*96] = __float2bfloat16(acc);
    }
}

__global__ __launch_bounds__(256) void dwconv(
    const __hip_bfloat16* __restrict__ qkv,
    const float* __restrict__ w3, const float* __restrict__ b3,
    const float* __restrict__ w5, const float* __restrict__ b5,
    const float* __restrict__ w7, const float* __restrict__ b7,
    __hip_bfloat16* __restrict__ cv)
{
    const int b  = blockIdx.z;
    const int ch = blockIdx.y * 128 + (threadIdx.x & 127);   // 0..767
    const int p0 = blockIdx.x * 16 + (threadIdx.x >> 7) * 8; // 16 px / block
    const int hh = ch / 96, d = ch % 96;
    const __hip_bfloat16* vb  = qkv + (size_t)b*NN*2304 + 2304 + 1536 + ch; // token 1
    __hip_bfloat16* cvb = cv + (size_t)(b*8 + hh)*HW*96 + d;
    if (ch < 192)      dw_run<3>(vb, w3 + ch*9,        b3[ch],     cvb, p0);
    else if (ch < 480) dw_run<5>(vb, w5 + (ch-192)*25, b5[ch-192], cvb, p0);
    else               dw_run<7>(vb, w7 + (ch-480)*49, b7[ch-480], cvb, p0);
}

// ---------------- att = scale * (q @ kv) + pad(q_img * conv_v) ----------------
__global__ __launch_bounds__(384) void assemble(
    const __hip_bfloat16* __restrict__ qkv,
    const float* __restrict__ kvmat,
    const __hip_bfloat16* __restrict__ cv,
    __hip_bfloat16* __restrict__ att)   // = qkv + 768 (dead k-section), ld 2304
{
    const int tile = blockIdx.x, h = blockIdx.y, b = blockIdx.z;
    __shared__ float kv_s[9216];
    __shared__ alignas(16) float q_s[4][96];
    const int t = threadIdx.x;
    const float* kg = kvmat + (size_t)(b*8 + h)*9216;
    for (int i = t; i < 9216; i += 384) kv_s[i] = kg[i];
    const int d = t % 96, sub = t / 96;  // 4 tokens in flight
    const __hip_bfloat16* qb  = qkv + (size_t)b*NN*2304 + h*96;
    const __hip_bfloat16* cvb = cv  + (size_t)(b*8 + h)*HW*96 + d;
    __syncthreads();
    for (int it = 0; it < 32; ++it) {
        const int n = tile*128 + it*4 + sub;
        const bool valid = n < NN;
        const float qv = valid ? __bfloat162float(qb[(size_t)n*2304 + d]) : 0.f;
        __syncthreads();
        q_s[sub][d] = qv;
        __syncthreads();
        if (valid) {
            float fa = 0.f;
#pragma unroll
            for (int c4 = 0; c4 < 24; ++c4) {
                const float4 q4 = *(const float4*)&q_s[sub][c4*4];
                fa += q4.x * kv_s[(c4*4+0)*96 + d];
                fa += q4.y * kv_s[(c4*4+1)*96 + d];
                fa += q4.z * kv_s[(c4*4+2)*96 + d];
                fa += q4.w * kv_s[(c4*4+3)*96 + d];
            }
            float outv = 0.10206207261596577f * fa;   // 96^-0.5
            if (n > 0) outv += qv * __bfloat162float(cvb[(size_t)(n-1)*96]);
            att[(size_t)(b*NN + n)*2304 + h*96 + d] = __float2bfloat16(outv);
        }
    }
}

extern "C" void kernel_launch(void* const* d_in, const int* in_sizes, int n_in,
                              void* d_out, int out_size, void* d_ws, size_t ws_size,
                              hipStream_t stream)
{
    const float* x      = (const float*)d_in[0];
    const float* qkv_w  = (const float*)d_in[1];
    const float* qkv_b  = (const float*)d_in[2];
    const float* proj_w = (const float*)d_in[3];
    const float* proj_b = (const float*)d_in[4];
    const float* w3 = (const float*)d_in[5];
    const float* b3 = (const float*)d_in[6];
    const float* w5 = (const float*)d_in[7];
    const float* b5 = (const float*)d_in[8];
    const float* w7 = (const float*)d_in[9];
    const float* b7 = (const float*)d_in[10];
    float* out = (float*)d_out;

    // ws layout (bf16 intermediates; needs ~156.6 MB)
    char* ws = (char*)d_ws;
    const size_t QKV_B = (size_t)MTOK * 2304 * 2;       // 115,642,368
    const size_t CV_B  = (size_t)64 * HW * 96 * 2;      //  38,535,168
    const size_t KV_B  = (size_t)64 * 9216 * 4;         //   2,359,296
    if (ws_size < QKV_B + CV_B + KV_B + 49152) return;  // fail loudly (wrong output)
    __hip_bfloat16* qkv  = (__hip_bfloat16*)ws;
    __hip_bfloat16* cv   = (__hip_bfloat16*)(ws + QKV_B);
    float*          kvm  = (float*)(ws + QKV_B + CV_B);
    float*          stat = (float*)(ws + QKV_B + CV_B + KV_B);

    // 1) qkv = x @ qkv_w^T + b   -> [25096, 2304] bf16
    gemm_nt<true,false><<<dim3(18, 197), 256, 0, stream>>>(
        x, 768, qkv_w, qkv_b, qkv, 2304, MTOK, 2304, 768);
    // 2) zero kv accumulator
    zero_f32<<<2304, 256, 0, stream>>>(kvm, 64*9216);
    // 3) per-column softmax stats of k
    ksm_stats<<<24, 256, 0, stream>>>(qkv, stat);
    // 4) kv = softmax(k)^T @ v  (atomic partial sums over 8 N-chunks)
    kv_accum<<<dim3(64, 8), 256, 0, stream>>>(qkv, stat, kvm);
    // 5) depthwise conv on v image -> cv [b,h,pix,d] bf16
    dwconv<<<dim3(196, 6, 8), 256, 0, stream>>>(qkv, w3, b3, w5, b5, w7, b7, cv);
    // 6) att = scale * q@kv + crpe  -> overwrite dead k-section of qkv buffer
    assemble<<<dim3(25, 8, 8), 384, 0, stream>>>(qkv, kvm, cv,
                                                 (__hip_bfloat16*)ws + 768);
    // 7) out = att @ proj_w^T + proj_b  -> f32 d_out
    gemm_nt<false,true><<<dim3(6, 197), 256, 0, stream>>>(
        (const unsigned short*)ws + 768, 2304, proj_w, proj_b, out, 768,
        MTOK, 768, 768);
}

// Round 4
// 1194.759 us; speedup vs baseline: 1.3485x; 1.3485x over previous
//
#include <hip/hip_runtime.h>
#include <hip/hip_bf16.h>

// CoaT factorized attention + conv rel-pos-enc. B=8 N=3137 C=768 h=8 c=96 H=W=56.
// All harness tensors are FLOAT32 (per reference). Compute uses bf16 MFMA with
// f32->bf16 conversion at staging; intermediates in ws are bf16; accum fp32.

#define BB 8
#define NN 3137
#define HH 8
#define CH 96
#define HW 3136
#define IMG 56
#define MTOK (BB*NN)   // 25096

typedef __bf16 bf16x8 __attribute__((ext_vector_type(8)));
typedef unsigned short u16x8 __attribute__((ext_vector_type(8)));
typedef float  f32x4  __attribute__((ext_vector_type(4)));
typedef float  f32x8  __attribute__((ext_vector_type(8)));

__device__ __forceinline__ bf16x8 cvt_f32x8_bf16(f32x8 v) {
    return __builtin_convertvector(v, bf16x8);
}

// ---------------- GEMM (NT): C[M,Nd] = A[M,K](lda) @ W[Nd,K]^T + bias ----------------
// 128x128 block tile, BK=32, 4 waves each 64x64 (4x4 of 16x16x32 mfma).
template<bool A_F32, bool OUT_F32>
__global__ __launch_bounds__(256) void gemm_nt(
    const void* __restrict__ Aptr, int lda,
    const float* __restrict__ W,
    const float* __restrict__ bias,
    void* __restrict__ Cptr, int ldc,
    int M, int Nd, int K)
{
    __shared__ alignas(16) unsigned short As[128*32];
    __shared__ alignas(16) unsigned short Bs[128*32];
    const int tid  = threadIdx.x;
    const int n0   = blockIdx.x * 128;
    const int m0   = blockIdx.y * 128;
    const int lane = tid & 63;
    const int wave = tid >> 6;
    const int wm   = (wave >> 1) * 64;
    const int wn   = (wave & 1) * 64;
    const int lr   = lane & 15;
    const int quad = lane >> 4;

    const int r0 = tid >> 2, c0 = (tid & 3) * 8;
    const int r1 = r0 + 64;
    int am0 = m0 + r0; if (am0 > M-1) am0 = M-1;
    int am1 = m0 + r1; if (am1 > M-1) am1 = M-1;
    const float* w0 = W + (size_t)(n0+r0)*K + c0;
    const float* w1 = W + (size_t)(n0+r1)*K + c0;
    unsigned short* lA0 = As + tid*8;
    unsigned short* lA1 = As + (tid+256)*8;
    unsigned short* lB0 = Bs + tid*8;
    unsigned short* lB1 = Bs + (tid+256)*8;

    const float* af0 = A_F32 ? ((const float*)Aptr + (size_t)am0*lda + c0) : nullptr;
    const float* af1 = A_F32 ? ((const float*)Aptr + (size_t)am1*lda + c0) : nullptr;
    const unsigned short* ab0 = A_F32 ? nullptr : ((const unsigned short*)Aptr + (size_t)am0*lda + c0);
    const unsigned short* ab1 = A_F32 ? nullptr : ((const unsigned short*)Aptr + (size_t)am1*lda + c0);

    f32x4 acc[4][4] = {};
    for (int k0 = 0; k0 < K; k0 += 32) {
        u16x8 ra0, ra1;
        if (A_F32) {
            ra0 = (u16x8)cvt_f32x8_bf16(*(const f32x8*)(af0 + k0));
            ra1 = (u16x8)cvt_f32x8_bf16(*(const f32x8*)(af1 + k0));
        } else {
            ra0 = *(const u16x8*)(ab0 + k0);
            ra1 = *(const u16x8*)(ab1 + k0);
        }
        const u16x8 rb0 = (u16x8)cvt_f32x8_bf16(*(const f32x8*)(w0 + k0));
        const u16x8 rb1 = (u16x8)cvt_f32x8_bf16(*(const f32x8*)(w1 + k0));
        __syncthreads();                   // previous iter's LDS reads done
        *(u16x8*)lA0 = ra0;
        *(u16x8*)lA1 = ra1;
        *(u16x8*)lB0 = rb0;
        *(u16x8*)lB1 = rb1;
        __syncthreads();
        bf16x8 af[4], bfr[4];
#pragma unroll
        for (int i = 0; i < 4; ++i) {
            af[i]  = *(const bf16x8*)(As + (wm + i*16 + lr)*32 + quad*8);
            bfr[i] = *(const bf16x8*)(Bs + (wn + i*16 + lr)*32 + quad*8);
        }
#pragma unroll
        for (int i = 0; i < 4; ++i)
#pragma unroll
            for (int j = 0; j < 4; ++j)
                acc[i][j] = __builtin_amdgcn_mfma_f32_16x16x32_bf16(af[i], bfr[j], acc[i][j], 0, 0, 0);
    }
    // epilogue: C/D layout col=lane&15, row=quad*4+reg (m89-verified)
#pragma unroll
    for (int j = 0; j < 4; ++j) {
        const int col = n0 + wn + j*16 + lr;
        const float bv = bias[col];
#pragma unroll
        for (int i = 0; i < 4; ++i) {
#pragma unroll
            for (int r = 0; r < 4; ++r) {
                const int row = m0 + wm + i*16 + quad*4 + r;
                if (row < M) {
                    const float v = acc[i][j][r] + bv;
                    if (OUT_F32)
                        ((float*)Cptr)[(size_t)row*ldc + col] = v;
                    else
                        ((__hip_bfloat16*)Cptr)[(size_t)row*ldc + col] = __float2bfloat16(v);
                }
            }
        }
    }
}

// ---------------- softmax stats over tokens: per (b, h*96+c) column ----------------
__global__ __launch_bounds__(256) void ksm_stats(
    const __hip_bfloat16* __restrict__ qkv, float* __restrict__ stats)
{
    const int g  = blockIdx.x * 256 + threadIdx.x;     // 0..6143
    const int b  = g / 768, hc = g % 768;
    const __hip_bfloat16* base = qkv + (size_t)b*NN*2304 + 768 + hc;
    float m[4] = {-1e30f,-1e30f,-1e30f,-1e30f}, s[4] = {0.f,0.f,0.f,0.f};
    int n = 0;
    for (; n + 4 <= NN; n += 4) {
#pragma unroll
        for (int j = 0; j < 4; ++j) {
            const float x = __bfloat162float(base[(size_t)(n+j)*2304]);
            const float mn = fmaxf(m[j], x);
            s[j] = s[j]*__expf(m[j]-mn) + __expf(x-mn);
            m[j] = mn;
        }
    }
    for (; n < NN; ++n) {
        const float x = __bfloat162float(base[(size_t)n*2304]);
        const float mn = fmaxf(m[0], x);
        s[0] = s[0]*__expf(m[0]-mn) + __expf(x-mn);
        m[0] = mn;
    }
    const float M2 = fmaxf(fmaxf(m[0],m[1]), fmaxf(m[2],m[3]));
    const float S  = s[0]*__expf(m[0]-M2) + s[1]*__expf(m[1]-M2)
                   + s[2]*__expf(m[2]-M2) + s[3]*__expf(m[3]-M2);
    stats[2*g]   = M2;
    stats[2*g+1] = S;
}

__global__ __launch_bounds__(256) void zero_f32(float* __restrict__ p, int n)
{
    const int i = blockIdx.x * 256 + threadIdx.x;
    if (i < n) p[i] = 0.f;
}

// ---------------- kv[b,h,c,d] = sum_n softmax(k)[n,c] * v[n,d] ----------------
__global__ __launch_bounds__(256) void kv_accum(
    const __hip_bfloat16* __restrict__ qkv,
    const float* __restrict__ stats,
    float* __restrict__ kvmat)
{
    const int bh = blockIdx.x;              // 0..63
    const int b = bh >> 3, h = bh & 7;
    const int nstart = blockIdx.y * 393;
    int nend = nstart + 393; if (nend > NN) nend = NN;
    __shared__ float smax[96], srs[96];
    __shared__ float krow[4][96], vrow[4][96];
    const int t = threadIdx.x;
    if (t < 96) {
        const int g = b*768 + h*96 + t;
        smax[t] = stats[2*g];
        srs[t]  = 1.0f / stats[2*g+1];
    }
    __syncthreads();
    const int ci = (t >> 4) * 6;            // 16 groups of 6 over c
    const int di = (t & 15) * 6;            // 16 groups of 6 over d
    const __hip_bfloat16* kb = qkv + (size_t)b*NN*2304 + 768 + h*96;
    const __hip_bfloat16* vb = kb + 768;
    float acc[6][6] = {};
    for (int n = nstart; n < nend; n += 4) {
        __syncthreads();
        for (int idx = t; idx < 384; idx += 256) {
            const int r = idx / 96, j = idx % 96;
            const int nn = n + r;
            if (nn < nend) {
                krow[r][j] = __expf(__bfloat162float(kb[(size_t)nn*2304 + j]) - smax[j]) * srs[j];
                vrow[r][j] = __bfloat162float(vb[(size_t)nn*2304 + j]);
            } else { krow[r][j] = 0.f; vrow[r][j] = 0.f; }
        }
        __syncthreads();
#pragma unroll
        for (int r = 0; r < 4; ++r) {
            float kf[6], vf[6];
#pragma unroll
            for (int i = 0; i < 6; ++i) kf[i] = krow[r][ci+i];
#pragma unroll
            for (int j = 0; j < 6; ++j) vf[j] = vrow[r][di+j];
#pragma unroll
            for (int i = 0; i < 6; ++i)
#pragma unroll
                for (int j = 0; j < 6; ++j)
                    acc[i][j] += kf[i] * vf[j];
        }
    }
    float* outp = kvmat + (size_t)bh*9216;
#pragma unroll
    for (int i = 0; i < 6; ++i)
#pragma unroll
        for (int j = 0; j < 6; ++j)
            atomicAdd(&outp[(ci+i)*96 + (di+j)], acc[i][j]);
}

// ---------------- depthwise conv v2: LDS row-band ring, 32-ch groups ----------------
// Block = (y-band of 14 rows, 32-channel group, batch). LDS ring vt[8][64][36] f32:
// [ring-row][x' = x+4 (zero-padded halo)][ch (+4 pad: bank = (4x'+ch)%32, conflict-free)].
// Each thread: one ch, 7 consecutive x outputs; register sliding window per dy.
template<int KS>
__device__ __forceinline__ void dw_band(
    float (*vt)[64][36],
    const __hip_bfloat16* __restrict__ vbase,  // qkv + b*NN*2304 + 2304 + 1536 + chbase
    const float* __restrict__ wp, float bv,
    __hip_bfloat16* __restrict__ cvo,          // cv + ((b*8+h)*3136)*96 + d
    int y0)
{
    constexpr int P = KS/2;
    const int t = threadIdx.x;
    float wr[KS*KS];
#pragma unroll
    for (int i = 0; i < KS*KS; ++i) wr[i] = wp[i];

    const int spx = t >> 2, sc0 = (t & 3) * 8;     // staging map: 4 threads/pixel
    const int ch = t & 31, xs = t >> 5;            // compute map: 32 ch x 8 x-slots
    const int xbase = xs*7 + 4 - P;

    // prologue: stage rows y0-P .. y0+P-1
#pragma unroll
    for (int r = -P; r < P; ++r) {
        const int y = y0 + r;
        if (t < 224) {
            f32x8 v8 = {0,0,0,0,0,0,0,0};
            if ((unsigned)y < (unsigned)IMG) {
                const bf16x8 rv = *(const bf16x8*)(vbase + (size_t)(y*IMG + spx)*2304 + sc0);
                v8 = __builtin_convertvector(rv, f32x8);
            }
            float* dst = &vt[(y+8)&7][spx+4][sc0];
            *(f32x4*)dst     = *(f32x4*)&v8;
            *(f32x4*)(dst+4) = *((f32x4*)&v8 + 1);
        }
    }

    for (int yy = y0; yy < y0 + 14; ++yy) {
        {   // stage row yy+P (overwrites ring slot last needed by row yy-2)
            const int y = yy + P;
            if (t < 224) {
                f32x8 v8 = {0,0,0,0,0,0,0,0};
                if ((unsigned)y < (unsigned)IMG) {
                    const bf16x8 rv = *(const bf16x8*)(vbase + (size_t)(y*IMG + spx)*2304 + sc0);
                    v8 = __builtin_convertvector(rv, f32x8);
                }
                float* dst = &vt[(y+8)&7][spx+4][sc0];
                *(f32x4*)dst     = *(f32x4*)&v8;
                *(f32x4*)(dst+4) = *((f32x4*)&v8 + 1);
            }
        }
        __syncthreads();
        float acc[7];
#pragma unroll
        for (int j = 0; j < 7; ++j) acc[j] = bv;
        for (int dy = 0; dy < KS; ++dy) {
            const float* rowp = &vt[(yy + dy - P + 8) & 7][0][ch] + xbase*36;
            float win[7 + 2*P];
#pragma unroll
            for (int i = 0; i < 7 + 2*P; ++i) win[i] = rowp[i*36];
#pragma unroll
            for (int dx = 0; dx < KS; ++dx)
#pragma unroll
                for (int j = 0; j < 7; ++j)
                    acc[j] += wr[dy*KS+dx] * win[j+dx];
        }
        const int p0 = yy*IMG + xs*7;
#pragma unroll
        for (int j = 0; j < 7; ++j)
            cvo[(size_t)(p0 + j)*96] = __float2bfloat16(acc[j]);
        __syncthreads();   // compute done before next stage overwrites
    }
}

__global__ __launch_bounds__(256) void dwconv2(
    const __hip_bfloat16* __restrict__ qkv,
    const float* __restrict__ w3, const float* __restrict__ b3,
    const float* __restrict__ w5, const float* __restrict__ b5,
    const float* __restrict__ w7, const float* __restrict__ b7,
    __hip_bfloat16* __restrict__ cv)
{
    __shared__ float vt[8][64][36];
    const int band = blockIdx.x, grp = blockIdx.y, b = blockIdx.z;
    const int t = threadIdx.x;
    // zero the x-halo pads (x' in {0..3, 60..63}) for all 8 ring rows, once
    {
        const int s = t >> 5, i = t & 31;
        const int xi = i >> 2;
        const int xp = (xi < 4) ? xi : 56 + xi;
        const int c0 = (i & 3) * 8;
        const f32x4 z = {0.f, 0.f, 0.f, 0.f};
        *(f32x4*)&vt[s][xp][c0]     = z;
        *(f32x4*)&vt[s][xp][c0+4]   = z;
    }
    // no barrier needed before first compute-read: dw_band's first __syncthreads
    // (after the first stage) makes pads + staged rows visible together.
    const int chbase = grp * 32;
    const int wg = chbase + (t & 31);
    const int h = wg / 96, d = wg % 96;
    const int y0 = band * 14;
    const __hip_bfloat16* vbase = qkv + (size_t)b*NN*2304 + 2304 + 1536 + chbase;
    __hip_bfloat16* cvo = cv + ((size_t)(b*8 + h)*HW)*96 + d;
    if (grp < 6)        dw_band<3>(vt, vbase, w3 + wg*9,        b3[wg],     cvo, y0);
    else if (grp < 15)  dw_band<5>(vt, vbase, w5 + (wg-192)*25, b5[wg-192], cvo, y0);
    else                dw_band<7>(vt, vbase, w7 + (wg-480)*49, b7[wg-480], cvo, y0);
}

// ---------------- att = scale * (q @ kv) + pad(q_img * conv_v) ----------------
__global__ __launch_bounds__(384) void assemble(
    const __hip_bfloat16* __restrict__ qkv,
    const float* __restrict__ kvmat,
    const __hip_bfloat16* __restrict__ cv,
    __hip_bfloat16* __restrict__ att)   // = qkv + 768 (dead k-section), ld 2304
{
    const int tile = blockIdx.x, h = blockIdx.y, b = blockIdx.z;
    __shared__ float kv_s[9216];
    __shared__ alignas(16) float q_s[4][96];
    const int t = threadIdx.x;
    const float* kg = kvmat + (size_t)(b*8 + h)*9216;
    for (int i = t; i < 9216; i += 384) kv_s[i] = kg[i];
    const int d = t % 96, sub = t / 96;  // 4 tokens in flight
    const __hip_bfloat16* qb  = qkv + (size_t)b*NN*2304 + h*96;
    const __hip_bfloat16* cvb = cv  + (size_t)(b*8 + h)*HW*96 + d;
    __syncthreads();
    for (int it = 0; it < 32; ++it) {
        const int n = tile*128 + it*4 + sub;
        const bool valid = n < NN;
        const float qv = valid ? __bfloat162float(qb[(size_t)n*2304 + d]) : 0.f;
        __syncthreads();
        q_s[sub][d] = qv;
        __syncthreads();
        if (valid) {
            float fa = 0.f;
#pragma unroll
            for (int c4 = 0; c4 < 24; ++c4) {
                const float4 q4 = *(const float4*)&q_s[sub][c4*4];
                fa += q4.x * kv_s[(c4*4+0)*96 + d];
                fa += q4.y * kv_s[(c4*4+1)*96 + d];
                fa += q4.z * kv_s[(c4*4+2)*96 + d];
                fa += q4.w * kv_s[(c4*4+3)*96 + d];
            }
            float outv = 0.10206207261596577f * fa;   // 96^-0.5
            if (n > 0) outv += qv * __bfloat162float(cvb[(size_t)(n-1)*96]);
            att[(size_t)(b*NN + n)*2304 + h*96 + d] = __float2bfloat16(outv);
        }
    }
}

extern "C" void kernel_launch(void* const* d_in, const int* in_sizes, int n_in,
                              void* d_out, int out_size, void* d_ws, size_t ws_size,
                              hipStream_t stream)
{
    const float* x      = (const float*)d_in[0];
    const float* qkv_w  = (const float*)d_in[1];
    const float* qkv_b  = (const float*)d_in[2];
    const float* proj_w = (const float*)d_in[3];
    const float* proj_b = (const float*)d_in[4];
    const float* w3 = (const float*)d_in[5];
    const float* b3 = (const float*)d_in[6];
    const float* w5 = (const float*)d_in[7];
    const float* b5 = (const float*)d_in[8];
    const float* w7 = (const float*)d_in[9];
    const float* b7 = (const float*)d_in[10];
    float* out = (float*)d_out;

    // ws layout (bf16 intermediates; needs ~156.6 MB)
    char* ws = (char*)d_ws;
    const size_t QKV_B = (size_t)MTOK * 2304 * 2;       // 115,642,368
    const size_t CV_B  = (size_t)64 * HW * 96 * 2;      //  38,535,168
    const size_t KV_B  = (size_t)64 * 9216 * 4;         //   2,359,296
    if (ws_size < QKV_B + CV_B + KV_B + 49152) return;  // fail loudly (wrong output)
    __hip_bfloat16* qkv  = (__hip_bfloat16*)ws;
    __hip_bfloat16* cv   = (__hip_bfloat16*)(ws + QKV_B);
    float*          kvm  = (float*)(ws + QKV_B + CV_B);
    float*          stat = (float*)(ws + QKV_B + CV_B + KV_B);

    // 1) qkv = x @ qkv_w^T + b   -> [25096, 2304] bf16
    gemm_nt<true,false><<<dim3(18, 197), 256, 0, stream>>>(
        x, 768, qkv_w, qkv_b, qkv, 2304, MTOK, 2304, 768);
    // 2) zero kv accumulator
    zero_f32<<<2304, 256, 0, stream>>>(kvm, 64*9216);
    // 3) per-column softmax stats of k
    ksm_stats<<<24, 256, 0, stream>>>(qkv, stat);
    // 4) kv = softmax(k)^T @ v  (atomic partial sums over 8 N-chunks)
    kv_accum<<<dim3(64, 8), 256, 0, stream>>>(qkv, stat, kvm);
    // 5) depthwise conv on v image -> cv [b,h,pix,d] bf16  (LDS row-band v2)
    dwconv2<<<dim3(4, 24, 8), 256, 0, stream>>>(qkv, w3, b3, w5, b5, w7, b7, cv);
    // 6) att = scale * q@kv + crpe  -> overwrite dead k-section of qkv buffer
    assemble<<<dim3(25, 8, 8), 384, 0, stream>>>(qkv, kvm, cv,
                                                 (__hip_bfloat16*)ws + 768);
    // 7) out = att @ proj_w^T + proj_b  -> f32 d_out
    gemm_nt<false,true><<<dim3(6, 197), 256, 0, stream>>>(
        (const unsigned short*)ws + 768, 2304, proj_w, proj_b, out, 768,
        MTOK, 768, 768);
}

// Round 5
// 1094.090 us; speedup vs baseline: 1.4726x; 1.0920x over previous
//
#include <hip/hip_runtime.h>
#include <hip/hip_bf16.h>

// CoaT factorized attention + conv rel-pos-enc. B=8 N=3137 C=768 h=8 c=96 H=W=56.
// Harness tensors are FLOAT32. Compute: pre-convert x/weights to bf16 once, then
// m97-style async-LDS bf16 MFMA GEMMs; intermediates bf16; accumulation fp32.

#define BB 8
#define NN 3137
#define HH 8
#define CH 96
#define HW 3136
#define IMG 56
#define MTOK (BB*NN)   // 25096

typedef __bf16 bf16x8 __attribute__((ext_vector_type(8)));
typedef unsigned short u16x8 __attribute__((ext_vector_type(8)));
typedef float  f32x4  __attribute__((ext_vector_type(4)));
typedef float  f32x8  __attribute__((ext_vector_type(8)));

__device__ __forceinline__ void gl_lds16(const void* g, void* l) {
    __builtin_amdgcn_global_load_lds(
        (const __attribute__((address_space(1))) unsigned int*)g,
        (__attribute__((address_space(3))) unsigned int*)l, 16, 0, 0);
}

// ---------------- f32 -> bf16 bulk convert (n8 = element_count/8) ----------------
__global__ __launch_bounds__(256) void cvt_bf16(
    const float* __restrict__ in, unsigned short* __restrict__ out, int n8)
{
    const int i = blockIdx.x * 256 + threadIdx.x;
    if (i < n8) {
        const f32x8 v = ((const f32x8*)in)[i];
        ((u16x8*)out)[i] = (u16x8)__builtin_convertvector(v, bf16x8);
    }
}

// ---------------- GEMM (NT): C[M,Nd] = A[M,K](lda,bf16) @ W[Nd,K]^T(bf16) + bias ----------------
// 128x128 tile, BK=32, 4 waves 64x64 (4x4 of 16x16x32 mfma), global_load_lds width=16.
template<bool OUT_F32>
__global__ __launch_bounds__(256) void gemm_bt(
    const unsigned short* __restrict__ A, int lda,
    const unsigned short* __restrict__ W,
    const float* __restrict__ bias,
    void* __restrict__ Cptr, int ldc,
    int M, int Nd, int K)
{
    __shared__ alignas(16) unsigned short As[128*32];
    __shared__ alignas(16) unsigned short Bs[128*32];
    const int tid  = threadIdx.x;
    const int n0   = blockIdx.x * 128;
    const int m0   = blockIdx.y * 128;
    const int lane = tid & 63;
    const int wave = tid >> 6;
    const int wm   = (wave >> 1) * 64;
    const int wn   = (wave & 1) * 64;
    const int lr   = lane & 15;
    const int quad = lane >> 4;

    // staging: slot s in [0,512): row = s>>2, kcol = (s&3)*8 ; 16B per slot
    const int r0 = tid >> 2, c0 = (tid & 3) * 8;
    const int r1 = r0 + 64;
    int am0 = m0 + r0; if (am0 > M-1) am0 = M-1;
    int am1 = m0 + r1; if (am1 > M-1) am1 = M-1;
    const unsigned short* a0 = A + (size_t)am0*lda + c0;
    const unsigned short* a1 = A + (size_t)am1*lda + c0;
    const unsigned short* w0 = W + (size_t)(n0+r0)*K + c0;
    const unsigned short* w1 = W + (size_t)(n0+r1)*K + c0;
    unsigned short* lA0 = As + tid*8;          // wave-uniform base + lane*16B (m104 rule)
    unsigned short* lA1 = As + (tid+256)*8;
    unsigned short* lB0 = Bs + tid*8;
    unsigned short* lB1 = Bs + (tid+256)*8;

    f32x4 acc[4][4] = {};
    for (int k0 = 0; k0 < K; k0 += 32) {
        __syncthreads();                       // previous iter's LDS reads done
        gl_lds16(a0 + k0, lA0);
        gl_lds16(a1 + k0, lA1);
        gl_lds16(w0 + k0, lB0);
        gl_lds16(w1 + k0, lB1);
        asm volatile("s_waitcnt vmcnt(0)" ::: "memory");
        __syncthreads();
        bf16x8 af[4], bfr[4];
#pragma unroll
        for (int i = 0; i < 4; ++i) {
            af[i]  = *(const bf16x8*)(As + (wm + i*16 + lr)*32 + quad*8);
            bfr[i] = *(const bf16x8*)(Bs + (wn + i*16 + lr)*32 + quad*8);
        }
#pragma unroll
        for (int i = 0; i < 4; ++i)
#pragma unroll
            for (int j = 0; j < 4; ++j)
                acc[i][j] = __builtin_amdgcn_mfma_f32_16x16x32_bf16(af[i], bfr[j], acc[i][j], 0, 0, 0);
    }
    // epilogue: C/D layout col=lane&15, row=quad*4+reg (m89-verified)
#pragma unroll
    for (int j = 0; j < 4; ++j) {
        const int col = n0 + wn + j*16 + lr;
        const float bv = bias[col];
#pragma unroll
        for (int i = 0; i < 4; ++i) {
#pragma unroll
            for (int r = 0; r < 4; ++r) {
                const int row = m0 + wm + i*16 + quad*4 + r;
                if (row < M) {
                    const float v = acc[i][j][r] + bv;
                    if (OUT_F32)
                        ((float*)Cptr)[(size_t)row*ldc + col] = v;
                    else
                        ((__hip_bfloat16*)Cptr)[(size_t)row*ldc + col] = __float2bfloat16(v);
                }
            }
        }
    }
}

// ---------------- softmax stats over tokens: per (b, h*96+c) column ----------------
__global__ __launch_bounds__(256) void ksm_stats(
    const __hip_bfloat16* __restrict__ qkv, float* __restrict__ stats)
{
    const int g  = blockIdx.x * 256 + threadIdx.x;     // 0..6143
    const int b  = g / 768, hc = g % 768;
    const __hip_bfloat16* base = qkv + (size_t)b*NN*2304 + 768 + hc;
    float m[4] = {-1e30f,-1e30f,-1e30f,-1e30f}, s[4] = {0.f,0.f,0.f,0.f};
    int n = 0;
    for (; n + 4 <= NN; n += 4) {
#pragma unroll
        for (int j = 0; j < 4; ++j) {
            const float x = __bfloat162float(base[(size_t)(n+j)*2304]);
            const float mn = fmaxf(m[j], x);
            s[j] = s[j]*__expf(m[j]-mn) + __expf(x-mn);
            m[j] = mn;
        }
    }
    for (; n < NN; ++n) {
        const float x = __bfloat162float(base[(size_t)n*2304]);
        const float mn = fmaxf(m[0], x);
        s[0] = s[0]*__expf(m[0]-mn) + __expf(x-mn);
        m[0] = mn;
    }
    const float M2 = fmaxf(fmaxf(m[0],m[1]), fmaxf(m[2],m[3]));
    const float S  = s[0]*__expf(m[0]-M2) + s[1]*__expf(m[1]-M2)
                   + s[2]*__expf(m[2]-M2) + s[3]*__expf(m[3]-M2);
    stats[2*g]   = M2;
    stats[2*g+1] = S;
}

__global__ __launch_bounds__(256) void zero_f32(float* __restrict__ p, int n)
{
    const int i = blockIdx.x * 256 + threadIdx.x;
    if (i < n) p[i] = 0.f;
}

// ---------------- kv[b,h,c,d] = sum_n softmax(k)[n,c] * v[n,d] ----------------
__global__ __launch_bounds__(256) void kv_accum(
    const __hip_bfloat16* __restrict__ qkv,
    const float* __restrict__ stats,
    float* __restrict__ kvmat)
{
    const int bh = blockIdx.x;              // 0..63
    const int b = bh >> 3, h = bh & 7;
    const int nstart = blockIdx.y * 393;
    int nend = nstart + 393; if (nend > NN) nend = NN;
    __shared__ float smax[96], srs[96];
    __shared__ float krow[4][96], vrow[4][96];
    const int t = threadIdx.x;
    if (t < 96) {
        const int g = b*768 + h*96 + t;
        smax[t] = stats[2*g];
        srs[t]  = 1.0f / stats[2*g+1];
    }
    __syncthreads();
    const int ci = (t >> 4) * 6;            // 16 groups of 6 over c
    const int di = (t & 15) * 6;            // 16 groups of 6 over d
    const __hip_bfloat16* kb = qkv + (size_t)b*NN*2304 + 768 + h*96;
    const __hip_bfloat16* vb = kb + 768;
    float acc[6][6] = {};
    for (int n = nstart; n < nend; n += 4) {
        __syncthreads();
        for (int idx = t; idx < 384; idx += 256) {
            const int r = idx / 96, j = idx % 96;
            const int nn = n + r;
            if (nn < nend) {
                krow[r][j] = __expf(__bfloat162float(kb[(size_t)nn*2304 + j]) - smax[j]) * srs[j];
                vrow[r][j] = __bfloat162float(vb[(size_t)nn*2304 + j]);
            } else { krow[r][j] = 0.f; vrow[r][j] = 0.f; }
        }
        __syncthreads();
#pragma unroll
        for (int r = 0; r < 4; ++r) {
            float kf[6], vf[6];
#pragma unroll
            for (int i = 0; i < 6; ++i) kf[i] = krow[r][ci+i];
#pragma unroll
            for (int j = 0; j < 6; ++j) vf[j] = vrow[r][di+j];
#pragma unroll
            for (int i = 0; i < 6; ++i)
#pragma unroll
                for (int j = 0; j < 6; ++j)
                    acc[i][j] += kf[i] * vf[j];
        }
    }
    float* outp = kvmat + (size_t)bh*9216;
#pragma unroll
    for (int i = 0; i < 6; ++i)
#pragma unroll
        for (int j = 0; j < 6; ++j)
            atomicAdd(&outp[(ci+i)*96 + (di+j)], acc[i][j]);
}

// ---------------- depthwise conv v2: LDS row-band ring, 32-ch groups ----------------
template<int KS>
__device__ __forceinline__ void dw_band(
    float (*vt)[64][36],
    const __hip_bfloat16* __restrict__ vbase,
    const float* __restrict__ wp, float bv,
    __hip_bfloat16* __restrict__ cvo,
    int y0)
{
    constexpr int P = KS/2;
    const int t = threadIdx.x;
    float wr[KS*KS];
#pragma unroll
    for (int i = 0; i < KS*KS; ++i) wr[i] = wp[i];

    const int spx = t >> 2, sc0 = (t & 3) * 8;     // staging map: 4 threads/pixel
    const int ch = t & 31, xs = t >> 5;            // compute map: 32 ch x 8 x-slots
    const int xbase = xs*7 + 4 - P;

#pragma unroll
    for (int r = -P; r < P; ++r) {
        const int y = y0 + r;
        if (t < 224) {
            f32x8 v8 = {0,0,0,0,0,0,0,0};
            if ((unsigned)y < (unsigned)IMG) {
                const bf16x8 rv = *(const bf16x8*)(vbase + (size_t)(y*IMG + spx)*2304 + sc0);
                v8 = __builtin_convertvector(rv, f32x8);
            }
            float* dst = &vt[(y+8)&7][spx+4][sc0];
            *(f32x4*)dst     = *(f32x4*)&v8;
            *(f32x4*)(dst+4) = *((f32x4*)&v8 + 1);
        }
    }

    for (int yy = y0; yy < y0 + 14; ++yy) {
        {
            const int y = yy + P;
            if (t < 224) {
                f32x8 v8 = {0,0,0,0,0,0,0,0};
                if ((unsigned)y < (unsigned)IMG) {
                    const bf16x8 rv = *(const bf16x8*)(vbase + (size_t)(y*IMG + spx)*2304 + sc0);
                    v8 = __builtin_convertvector(rv, f32x8);
                }
                float* dst = &vt[(y+8)&7][spx+4][sc0];
                *(f32x4*)dst     = *(f32x4*)&v8;
                *(f32x4*)(dst+4) = *((f32x4*)&v8 + 1);
            }
        }
        __syncthreads();
        float acc[7];
#pragma unroll
        for (int j = 0; j < 7; ++j) acc[j] = bv;
        for (int dy = 0; dy < KS; ++dy) {
            const float* rowp = &vt[(yy + dy - P + 8) & 7][0][ch] + xbase*36;
            float win[7 + 2*P];
#pragma unroll
            for (int i = 0; i < 7 + 2*P; ++i) win[i] = rowp[i*36];
#pragma unroll
            for (int dx = 0; dx < KS; ++dx)
#pragma unroll
                for (int j = 0; j < 7; ++j)
                    acc[j] += wr[dy*KS+dx] * win[j+dx];
        }
        const int p0 = yy*IMG + xs*7;
#pragma unroll
        for (int j = 0; j < 7; ++j)
            cvo[(size_t)(p0 + j)*96] = __float2bfloat16(acc[j]);
        __syncthreads();
    }
}

__global__ __launch_bounds__(256) void dwconv2(
    const __hip_bfloat16* __restrict__ qkv,
    const float* __restrict__ w3, const float* __restrict__ b3,
    const float* __restrict__ w5, const float* __restrict__ b5,
    const float* __restrict__ w7, const float* __restrict__ b7,
    __hip_bfloat16* __restrict__ cv)
{
    __shared__ float vt[8][64][36];
    const int band = blockIdx.x, grp = blockIdx.y, b = blockIdx.z;
    const int t = threadIdx.x;
    {
        const int s = t >> 5, i = t & 31;
        const int xi = i >> 2;
        const int xp = (xi < 4) ? xi : 56 + xi;
        const int c0 = (i & 3) * 8;
        const f32x4 z = {0.f, 0.f, 0.f, 0.f};
        *(f32x4*)&vt[s][xp][c0]     = z;
        *(f32x4*)&vt[s][xp][c0+4]   = z;
    }
    const int chbase = grp * 32;
    const int wg = chbase + (t & 31);
    const int h = wg / 96, d = wg % 96;
    const int y0 = band * 14;
    const __hip_bfloat16* vbase = qkv + (size_t)b*NN*2304 + 2304 + 1536 + chbase;
    __hip_bfloat16* cvo = cv + ((size_t)(b*8 + h)*HW)*96 + d;
    if (grp < 6)        dw_band<3>(vt, vbase, w3 + wg*9,        b3[wg],     cvo, y0);
    else if (grp < 15)  dw_band<5>(vt, vbase, w5 + (wg-192)*25, b5[wg-192], cvo, y0);
    else                dw_band<7>(vt, vbase, w7 + (wg-480)*49, b7[wg-480], cvo, y0);
}

// ---------------- att = scale * (q @ kv) + pad(q_img * conv_v) ----------------
__global__ __launch_bounds__(384) void assemble(
    const __hip_bfloat16* __restrict__ qkv,
    const float* __restrict__ kvmat,
    const __hip_bfloat16* __restrict__ cv,
    __hip_bfloat16* __restrict__ att)
{
    const int tile = blockIdx.x, h = blockIdx.y, b = blockIdx.z;
    __shared__ float kv_s[9216];
    __shared__ alignas(16) float q_s[4][96];
    const int t = threadIdx.x;
    const float* kg = kvmat + (size_t)(b*8 + h)*9216;
    for (int i = t; i < 9216; i += 384) kv_s[i] = kg[i];
    const int d = t % 96, sub = t / 96;
    const __hip_bfloat16* qb  = qkv + (size_t)b*NN*2304 + h*96;
    const __hip_bfloat16* cvb = cv  + (size_t)(b*8 + h)*HW*96 + d;
    __syncthreads();
    for (int it = 0; it < 32; ++it) {
        const int n = tile*128 + it*4 + sub;
        const bool valid = n < NN;
        const float qv = valid ? __bfloat162float(qb[(size_t)n*2304 + d]) : 0.f;
        __syncthreads();
        q_s[sub][d] = qv;
        __syncthreads();
        if (valid) {
            float fa = 0.f;
#pragma unroll
            for (int c4 = 0; c4 < 24; ++c4) {
                const float4 q4 = *(const float4*)&q_s[sub][c4*4];
                fa += q4.x * kv_s[(c4*4+0)*96 + d];
                fa += q4.y * kv_s[(c4*4+1)*96 + d];
                fa += q4.z * kv_s[(c4*4+2)*96 + d];
                fa += q4.w * kv_s[(c4*4+3)*96 + d];
            }
            float outv = 0.10206207261596577f * fa;   // 96^-0.5
            if (n > 0) outv += qv * __bfloat162float(cvb[(size_t)(n-1)*96]);
            att[(size_t)(b*NN + n)*2304 + h*96 + d] = __float2bfloat16(outv);
        }
    }
}

extern "C" void kernel_launch(void* const* d_in, const int* in_sizes, int n_in,
                              void* d_out, int out_size, void* d_ws, size_t ws_size,
                              hipStream_t stream)
{
    const float* x      = (const float*)d_in[0];
    const float* qkv_w  = (const float*)d_in[1];
    const float* qkv_b  = (const float*)d_in[2];
    const float* proj_w = (const float*)d_in[3];
    const float* proj_b = (const float*)d_in[4];
    const float* w3 = (const float*)d_in[5];
    const float* b3 = (const float*)d_in[6];
    const float* w5 = (const float*)d_in[7];
    const float* b5 = (const float*)d_in[8];
    const float* w7 = (const float*)d_in[9];
    const float* b7 = (const float*)d_in[10];
    float* out = (float*)d_out;

    // ws layout (~161.3 MB):
    //   qkv bf16 [25096,2304] | shared{ xb bf16 [25096,768] -> cv bf16 [64,3136,96] }
    //   | kvm f32 | stats | qkv_wb bf16 | proj_wb bf16
    char* ws = (char*)d_ws;
    const size_t QKV_B = (size_t)MTOK * 2304 * 2;       // 115,642,368
    const size_t XB_B  = (size_t)MTOK * 768 * 2;        //  38,547,456
    const size_t SH_B  = XB_B;                           //  >= CV_B (38,535,168)
    const size_t KV_B  = (size_t)64 * 9216 * 4;         //   2,359,296
    const size_t ST_B  = 49152;
    const size_t WB_B  = (size_t)2304 * 768 * 2;        //   3,538,944
    const size_t PW_B  = (size_t)768 * 768 * 2;         //   1,179,648
    if (ws_size < QKV_B + SH_B + KV_B + ST_B + WB_B + PW_B) return;
    __hip_bfloat16* qkv  = (__hip_bfloat16*)ws;
    unsigned short* xb   = (unsigned short*)(ws + QKV_B);
    __hip_bfloat16* cv   = (__hip_bfloat16*)(ws + QKV_B);           // reuses xb region
    float*          kvm  = (float*)(ws + QKV_B + SH_B);
    float*          stat = (float*)(ws + QKV_B + SH_B + KV_B);
    unsigned short* wb   = (unsigned short*)(ws + QKV_B + SH_B + KV_B + ST_B);
    unsigned short* pwb  = (unsigned short*)(ws + QKV_B + SH_B + KV_B + ST_B + WB_B);

    // 0) convert x and weights to bf16 (one-time; removes per-tile f32 staging)
    cvt_bf16<<<(MTOK*768/8 + 255)/256, 256, 0, stream>>>(x, xb, MTOK*768/8);
    cvt_bf16<<<(2304*768/8 + 255)/256, 256, 0, stream>>>(qkv_w, wb, 2304*768/8);
    cvt_bf16<<<(768*768/8 + 255)/256, 256, 0, stream>>>(proj_w, pwb, 768*768/8);
    // 1) qkv = x @ qkv_w^T + b   -> [25096, 2304] bf16
    gemm_bt<false><<<dim3(18, 197), 256, 0, stream>>>(
        xb, 768, wb, qkv_b, qkv, 2304, MTOK, 2304, 768);
    // 2) zero kv accumulator
    zero_f32<<<2304, 256, 0, stream>>>(kvm, 64*9216);
    // 3) per-column softmax stats of k
    ksm_stats<<<24, 256, 0, stream>>>(qkv, stat);
    // 4) kv = softmax(k)^T @ v
    kv_accum<<<dim3(64, 8), 256, 0, stream>>>(qkv, stat, kvm);
    // 5) depthwise conv on v image -> cv (overwrites dead xb)
    dwconv2<<<dim3(4, 24, 8), 256, 0, stream>>>(qkv, w3, b3, w5, b5, w7, b7, cv);
    // 6) att = scale * q@kv + crpe  -> dead k-section of qkv buffer
    assemble<<<dim3(25, 8, 8), 384, 0, stream>>>(qkv, kvm, cv,
                                                 (__hip_bfloat16*)ws + 768);
    // 7) out = att @ proj_w^T + proj_b  -> f32 d_out
    gemm_bt<true><<<dim3(6, 197), 256, 0, stream>>>(
        (const unsigned short*)ws + 768, 2304, pwb, proj_b, out, 768,
        MTOK, 768, 768);
}